// Round 3
// baseline (1687.081 us; speedup 1.0000x reference)
//
#include <hip/hip_runtime.h>
#include <hip/hip_bf16.h>

// ---------------------------------------------------------------------------
// B=2, S=2048, DM=4096, H=32, HKV=8, D=128, causal GQA attention.
//   q = X@Wq^T ; k = X@Wk^T ; v = X@Wv^T   (bt-GEMMs, bf16 MFMA, fp32 acc)
//   RoPE(q,k) ; flash attention ; out = attn@Wo^T (fp32 store)
//
// R3: inputs/outputs are FP32 (per reference dtype contract). Rounds 1-2
// produced NaN because fp32 buffers were read as bf16 (low mantissa halves
// interpreted as bf16 hit exponent=0xFF patterns -> NaN). The bf16 pipeline
// itself cannot generate NaN (max-subtracted softmax, li>=1). Fix: explicit
// fp32->bf16 conversion pass, bf16 MFMA compute, fp32 final store.
// ---------------------------------------------------------------------------

typedef __bf16 bf16x8 __attribute__((ext_vector_type(8)));
typedef __bf16 bf16x4 __attribute__((ext_vector_type(4)));
typedef float  f32x4  __attribute__((ext_vector_type(4)));

#define B_   2
#define S_   2048
#define DM_  4096
#define H_   32
#define HKV_ 8
#define D_   128

static __device__ __forceinline__ f32x4 mfma16(bf16x8 a, bf16x8 b, f32x4 c) {
    return __builtin_amdgcn_mfma_f32_16x16x32_bf16(a, b, c, 0, 0, 0);
}

// ---------------------------------------------------------------------------
// fp32 -> bf16 (RNE via cast), 4 elems/thread, n is a multiple of 4.
// ---------------------------------------------------------------------------
__global__ void f32_to_bf16(const float* __restrict__ src, __bf16* __restrict__ dst,
                            int n) {
    int idx = (blockIdx.x * blockDim.x + threadIdx.x) * 4;
    if (idx >= n) return;
    float4 v = *(const float4*)(src + idx);
    bf16x4 o;
    o[0] = (__bf16)v.x; o[1] = (__bf16)v.y; o[2] = (__bf16)v.z; o[3] = (__bf16)v.w;
    *(bf16x4*)(dst + idx) = o;
}

// ---------------------------------------------------------------------------
// bt-GEMM: C[m,n] = sum_k A[m,k]*B[n,k]. bf16 in, fp32 acc, OutT out.
// 128x128 tile, BK=64, 4 waves -> 64x64 each, 4x4 MFMA acc. LDS rows padded
// to 72 elems to break ds_read_b128 bank aliasing.
// ---------------------------------------------------------------------------
#define BK_   64
#define LDSW  72

template <typename OutT>
__global__ __launch_bounds__(256) void gemm_bt(const __bf16* __restrict__ A,
                                               const __bf16* __restrict__ Bm,
                                               OutT* __restrict__ C,
                                               int M, int N, int K) {
    __shared__ __align__(16) __bf16 As[128][LDSW];
    __shared__ __align__(16) __bf16 Bs[128][LDSW];
    const int tid  = threadIdx.x;
    const int lane = tid & 63;
    const int wave = tid >> 6;
    const int wm   = (wave >> 1) * 64;
    const int wn   = (wave & 1) * 64;
    const int m15  = lane & 15;
    const int q4   = lane >> 4;

    const __bf16* Ab = A  + (size_t)(blockIdx.x * 128) * K;
    const __bf16* Bb = Bm + (size_t)(blockIdx.y * 128) * K;

    f32x4 acc[4][4];
#pragma unroll
    for (int i = 0; i < 4; ++i)
#pragma unroll
        for (int j = 0; j < 4; ++j) acc[i][j] = (f32x4){0.f, 0.f, 0.f, 0.f};

    for (int k0 = 0; k0 < K; k0 += BK_) {
#pragma unroll
        for (int it = 0; it < 4; ++it) {
            int linear = it * 2048 + tid * 8;
            int row = linear >> 6;
            int col = linear & 63;
            *(bf16x8*)&As[row][col] = *(const bf16x8*)&Ab[(size_t)row * K + k0 + col];
            *(bf16x8*)&Bs[row][col] = *(const bf16x8*)&Bb[(size_t)row * K + k0 + col];
        }
        __syncthreads();
#pragma unroll
        for (int kk = 0; kk < 2; ++kk) {
            bf16x8 af[4], bfr[4];
#pragma unroll
            for (int i = 0; i < 4; ++i)
                af[i] = *(const bf16x8*)&As[wm + i * 16 + m15][kk * 32 + q4 * 8];
#pragma unroll
            for (int j = 0; j < 4; ++j)
                bfr[j] = *(const bf16x8*)&Bs[wn + j * 16 + m15][kk * 32 + q4 * 8];
#pragma unroll
            for (int i = 0; i < 4; ++i)
#pragma unroll
                for (int j = 0; j < 4; ++j)
                    acc[i][j] = mfma16(af[i], bfr[j], acc[i][j]);
        }
        __syncthreads();
    }
    // C/D layout: col = lane&15, row = (lane>>4)*4 + reg   [m89/m91 verified]
#pragma unroll
    for (int i = 0; i < 4; ++i)
#pragma unroll
        for (int j = 0; j < 4; ++j) {
            int row = blockIdx.x * 128 + wm + i * 16 + q4 * 4;
            int col = blockIdx.y * 128 + wn + j * 16 + m15;
#pragma unroll
            for (int r = 0; r < 4; ++r)
                C[(size_t)(row + r) * N + col] = (OutT)acc[i][j][r];
        }
}

// ---------------------------------------------------------------------------
// RoPE in-place on [B*S, nh*128]. angle = pos * 10000^(-i/64), i in [0,64).
// Precise sincosf (full range reduction; angles reach ~326 revolutions).
// ---------------------------------------------------------------------------
__global__ void rope_kernel(__bf16* __restrict__ X, const int* __restrict__ pos,
                            int nh, int total) {
    int idx = blockIdx.x * blockDim.x + threadIdx.x;
    if (idx >= total) return;
    int i  = idx & 63;
    int t  = idx >> 6;       // bs*nh + h
    int h  = t % nh;
    int bs = t / nh;
    float p   = (float)pos[bs];
    float inv = exp2f(-(float)i * 0.20762050593046326f); // log2(10000)/64
    float ang = p * inv;
    float s, c;
    sincosf(ang, &s, &c);
    __bf16* base = X + (size_t)bs * (nh * 128) + h * 128 + i;
    float x1 = (float)base[0];
    float x2 = (float)base[64];
    base[0]  = (__bf16)(x1 * c - x2 * s);
    base[64] = (__bf16)(x2 * c + x1 * s);
}

// ---------------------------------------------------------------------------
// V transpose: V [B*S, HKV*128] -> Vt [B, HKV, 128, S].
// ---------------------------------------------------------------------------
__global__ void transpose_v(const __bf16* __restrict__ V, __bf16* __restrict__ Vt,
                            int total) {
    int idx = blockIdx.x * blockDim.x + threadIdx.x;
    if (idx >= total) return;
    int s  = idx & (S_ - 1);
    int d  = (idx >> 11) & (D_ - 1);
    int hb = idx >> 18;              // b*HKV + h
    int b  = hb >> 3;
    int h  = hb & 7;
    Vt[idx] = V[((size_t)(b * S_ + s)) * (HKV_ * D_) + h * D_ + d];
}

// ---------------------------------------------------------------------------
// Flash attention, causal, GQA rep=4. One wave per (b,h,16-row Q tile).
// KV steps of 32 keys: 8 QK MFMAs (k=128) + online softmax + 8 PV MFMAs.
// P converts C-layout -> A-operand layout via per-wave LDS tile (m120).
// ---------------------------------------------------------------------------
__global__ __launch_bounds__(256) void attn_kernel(const __bf16* __restrict__ Q,
                                                   const __bf16* __restrict__ Kc,
                                                   const __bf16* __restrict__ Vt,
                                                   __bf16* __restrict__ O) {
    __shared__ __align__(16) __bf16 plds[4][16 * 32];
    const int wave = threadIdx.x >> 6;
    const int lane = threadIdx.x & 63;
    const int task = blockIdx.x * 4 + wave;
    const int qt = task & 127;
    const int h  = (task >> 7) & 31;
    const int b  = task >> 12;
    const int m15 = lane & 15;
    const int q4  = lane >> 4;
    const int hkv = h >> 2;
    const int qbase = qt * 16;

    const __bf16* qrow = Q + ((size_t)(b * S_ + qbase + m15)) * (H_ * D_) + h * D_;
    bf16x8 qf[4];
#pragma unroll
    for (int kk = 0; kk < 4; ++kk) qf[kk] = *(const bf16x8*)(qrow + kk * 32 + q4 * 8);

    f32x4 o[8];
#pragma unroll
    for (int t = 0; t < 8; ++t) o[t] = (f32x4){0.f, 0.f, 0.f, 0.f};
    float mi[4] = {-1e9f, -1e9f, -1e9f, -1e9f};
    float li[4] = {0.f, 0.f, 0.f, 0.f};

    const __bf16* Kbase = Kc + ((size_t)(b * S_)) * (HKV_ * D_) + hkv * D_;
    const __bf16* Vbase = Vt + ((size_t)((b * HKV_ + hkv) * D_)) * S_;
    const float scale = 0.08838834764831845f; // 1/sqrt(128)
    __bf16* pl = &plds[wave][0];

    for (int kb = 0; kb < qbase + 16; kb += 32) {
        const __bf16* k0p = Kbase + (size_t)(kb + m15) * (HKV_ * D_);
        const __bf16* k1p = k0p + (size_t)16 * (HKV_ * D_);
        bf16x8 kf0[4], kf1[4];
#pragma unroll
        for (int kk = 0; kk < 4; ++kk) {
            kf0[kk] = *(const bf16x8*)(k0p + kk * 32 + q4 * 8);
            kf1[kk] = *(const bf16x8*)(k1p + kk * 32 + q4 * 8);
        }
        f32x4 s0 = (f32x4){0.f, 0.f, 0.f, 0.f};
        f32x4 s1 = (f32x4){0.f, 0.f, 0.f, 0.f};
#pragma unroll
        for (int kk = 0; kk < 4; ++kk) {
            s0 = mfma16(qf[kk], kf0[kk], s0);
            s1 = mfma16(qf[kk], kf1[kk], s1);
        }
        float p0[4], p1[4], mx[4];
        const int key0 = kb + m15, key1 = kb + 16 + m15;
#pragma unroll
        for (int r = 0; r < 4; ++r) {
            int row = qbase + q4 * 4 + r;
            float v0 = s0[r] * scale; if (key0 > row) v0 = -1e9f;
            float v1 = s1[r] * scale; if (key1 > row) v1 = -1e9f;
            p0[r] = v0; p1[r] = v1; mx[r] = fmaxf(v0, v1);
        }
#pragma unroll
        for (int off = 1; off < 16; off <<= 1)
#pragma unroll
            for (int r = 0; r < 4; ++r) mx[r] = fmaxf(mx[r], __shfl_xor(mx[r], off));
        float al[4], rs[4];
#pragma unroll
        for (int r = 0; r < 4; ++r) {
            float mn = fmaxf(mi[r], mx[r]);
            al[r] = __expf(mi[r] - mn);
            mi[r] = mn;
            p0[r] = __expf(p0[r] - mn);
            p1[r] = __expf(p1[r] - mn);
            rs[r] = p0[r] + p1[r];
        }
#pragma unroll
        for (int off = 1; off < 16; off <<= 1)
#pragma unroll
            for (int r = 0; r < 4; ++r) rs[r] += __shfl_xor(rs[r], off);
#pragma unroll
        for (int r = 0; r < 4; ++r) li[r] = li[r] * al[r] + rs[r];
#pragma unroll
        for (int t = 0; t < 8; ++t)
#pragma unroll
            for (int r = 0; r < 4; ++r) o[t][r] *= al[r];
#pragma unroll
        for (int r = 0; r < 4; ++r) {
            pl[(q4 * 4 + r) * 32 + m15]      = (__bf16)p0[r];
            pl[(q4 * 4 + r) * 32 + 16 + m15] = (__bf16)p1[r];
        }
        bf16x8 pf = *(const bf16x8*)(pl + m15 * 32 + q4 * 8);
        const __bf16* vp = Vbase + kb + q4 * 8;
#pragma unroll
        for (int t = 0; t < 8; ++t) {
            bf16x8 vf = *(const bf16x8*)(vp + (size_t)(t * 16 + m15) * S_);
            o[t] = mfma16(pf, vf, o[t]);
        }
    }
    __bf16* ob = O + ((size_t)(b * S_ + qbase + q4 * 4)) * (H_ * D_) + h * D_;
#pragma unroll
    for (int t = 0; t < 8; ++t)
#pragma unroll
        for (int r = 0; r < 4; ++r)
            ob[(size_t)r * (H_ * D_) + t * 16 + m15] = (__bf16)(o[t][r] / li[r]);
}

// ---------------------------------------------------------------------------
extern "C" void kernel_launch(void* const* d_in, const int* in_sizes, int n_in,
                              void* d_out, int out_size, void* d_ws, size_t ws_size,
                              hipStream_t stream) {
    const float* X   = (const float*)d_in[0];
    const int*   pos = (const int*)d_in[1];
    const float* Wq  = (const float*)d_in[2];
    const float* Wk  = (const float*)d_in[3];
    const float* Wv  = (const float*)d_in[4];
    const float* Wo  = (const float*)d_in[5];
    float*       out = (float*)d_out;

    // Workspace layout (bytes), with aliasing:
    //   Xb   [0,          33554432)   fp32->bf16 X      (dead after V-gemm)
    //   Wqb  [33554432,   67108864)   bf16 Wq           (dead after Q-gemm)
    //   Wkb  [67108864,   75497472)
    //   Wvb  [75497472,   83886080)
    //   Wob  [83886080,  117440512)
    //   Qp   [117440512, 150994944)
    //   Kp   [150994944, 159383552)
    //   Vp   [159383552, 167772160)
    //   Vtp  = alias of Wqb region (8.4 MB <= 33.5 MB, Wqb dead)
    //   Attn = alias of Xb region   (Xb dead)
    char* ws = (char*)d_ws;
    __bf16* Xb   = (__bf16*)(ws);
    __bf16* Wqb  = (__bf16*)(ws + 33554432);
    __bf16* Wkb  = (__bf16*)(ws + 67108864);
    __bf16* Wvb  = (__bf16*)(ws + 75497472);
    __bf16* Wob  = (__bf16*)(ws + 83886080);
    __bf16* Qp   = (__bf16*)(ws + 117440512);
    __bf16* Kp   = (__bf16*)(ws + 150994944);
    __bf16* Vp   = (__bf16*)(ws + 159383552);
    __bf16* Vtp  = Wqb;   // alias
    __bf16* Attn = Xb;    // alias

    const int M  = B_ * S_;          // 4096
    const int nX = M * DM_;          // 16.7M
    const int nQ = H_ * D_ * DM_;    // 16.7M
    const int nK = HKV_ * D_ * DM_;  // 4.2M

    // fp32 -> bf16 conversions
    f32_to_bf16<<<(nX / 4 + 255) / 256, 256, 0, stream>>>(X,  Xb,  nX);
    f32_to_bf16<<<(nQ / 4 + 255) / 256, 256, 0, stream>>>(Wq, Wqb, nQ);
    f32_to_bf16<<<(nK / 4 + 255) / 256, 256, 0, stream>>>(Wk, Wkb, nK);
    f32_to_bf16<<<(nK / 4 + 255) / 256, 256, 0, stream>>>(Wv, Wvb, nK);
    f32_to_bf16<<<(nQ / 4 + 255) / 256, 256, 0, stream>>>(Wo, Wob, nQ);

    // QKV projections (bf16 out)
    gemm_bt<__bf16><<<dim3(M / 128, DM_ / 128), 256, 0, stream>>>(Xb, Wqb, Qp, M, H_ * D_, DM_);
    gemm_bt<__bf16><<<dim3(M / 128, (HKV_ * D_) / 128), 256, 0, stream>>>(Xb, Wkb, Kp, M, HKV_ * D_, DM_);
    gemm_bt<__bf16><<<dim3(M / 128, (HKV_ * D_) / 128), 256, 0, stream>>>(Xb, Wvb, Vp, M, HKV_ * D_, DM_);
    // RoPE
    {
        int totq = M * H_ * 64;
        rope_kernel<<<(totq + 255) / 256, 256, 0, stream>>>(Qp, pos, H_, totq);
        int totk = M * HKV_ * 64;
        rope_kernel<<<(totk + 255) / 256, 256, 0, stream>>>(Kp, pos, HKV_, totk);
    }
    // V transpose
    {
        int tot = B_ * HKV_ * D_ * S_;
        transpose_v<<<(tot + 255) / 256, 256, 0, stream>>>(Vp, Vtp, tot);
    }
    // attention
    attn_kernel<<<(B_ * H_ * (S_ / 16)) / 4, 256, 0, stream>>>(Qp, Kp, Vtp, Attn);
    // output projection (fp32 out)
    gemm_bt<float><<<dim3(M / 128, (H_ * D_) / 128), 256, 0, stream>>>(Attn, Wob, out, M, H_ * D_, DM_);
}

// Round 4
// 958.633 us; speedup vs baseline: 1.7599x; 1.7599x over previous
//
#include <hip/hip_runtime.h>
#include <hip/hip_bf16.h>

// ---------------------------------------------------------------------------
// B=2, S=2048, DM=4096, H=32, HKV=8, D=128, causal GQA attention.
//   q = X@Wq^T ; k = X@Wk^T ; v = X@Wv^T   (bt-GEMMs, bf16 MFMA, fp32 acc)
//   RoPE(q,k) ; flash attention ; out = attn@Wo^T (fp32 store)
//
// R4: attention rewritten as block-level flash attention. R3's per-wave
// global K/V loads (16 scattered 64B segments per instr, serial dep chain)
// left every pipe idle (MfmaUtil 2.7%). Now: 4 waves share LDS-staged
// K/V tiles (64 keys), 32 Q rows/wave, causal mask only on the 2 tail
// k-blocks, longest-tile-first ordering for load balance.
// ---------------------------------------------------------------------------

typedef __bf16 bf16x8 __attribute__((ext_vector_type(8)));
typedef __bf16 bf16x4 __attribute__((ext_vector_type(4)));
typedef float  f32x4  __attribute__((ext_vector_type(4)));

#define B_   2
#define S_   2048
#define DM_  4096
#define H_   32
#define HKV_ 8
#define D_   128

static __device__ __forceinline__ f32x4 mfma16(bf16x8 a, bf16x8 b, f32x4 c) {
    return __builtin_amdgcn_mfma_f32_16x16x32_bf16(a, b, c, 0, 0, 0);
}

// ---------------------------------------------------------------------------
// fp32 -> bf16 (RNE via cast), 4 elems/thread.
// ---------------------------------------------------------------------------
__global__ void f32_to_bf16(const float* __restrict__ src, __bf16* __restrict__ dst,
                            int n) {
    int idx = (blockIdx.x * blockDim.x + threadIdx.x) * 4;
    if (idx >= n) return;
    float4 v = *(const float4*)(src + idx);
    bf16x4 o;
    o[0] = (__bf16)v.x; o[1] = (__bf16)v.y; o[2] = (__bf16)v.z; o[3] = (__bf16)v.w;
    *(bf16x4*)(dst + idx) = o;
}

// ---------------------------------------------------------------------------
// bt-GEMM: C[m,n] = sum_k A[m,k]*B[n,k]. bf16 in, fp32 acc, OutT out.
// 128x128 tile, BK=64, 4 waves -> 64x64 each, 4x4 MFMA acc.
// ---------------------------------------------------------------------------
#define BK_   64
#define LDSW  72

template <typename OutT>
__global__ __launch_bounds__(256) void gemm_bt(const __bf16* __restrict__ A,
                                               const __bf16* __restrict__ Bm,
                                               OutT* __restrict__ C,
                                               int M, int N, int K) {
    __shared__ __align__(16) __bf16 As[128][LDSW];
    __shared__ __align__(16) __bf16 Bs[128][LDSW];
    const int tid  = threadIdx.x;
    const int lane = tid & 63;
    const int wave = tid >> 6;
    const int wm   = (wave >> 1) * 64;
    const int wn   = (wave & 1) * 64;
    const int m15  = lane & 15;
    const int q4   = lane >> 4;

    const __bf16* Ab = A  + (size_t)(blockIdx.x * 128) * K;
    const __bf16* Bb = Bm + (size_t)(blockIdx.y * 128) * K;

    f32x4 acc[4][4];
#pragma unroll
    for (int i = 0; i < 4; ++i)
#pragma unroll
        for (int j = 0; j < 4; ++j) acc[i][j] = (f32x4){0.f, 0.f, 0.f, 0.f};

    for (int k0 = 0; k0 < K; k0 += BK_) {
#pragma unroll
        for (int it = 0; it < 4; ++it) {
            int linear = it * 2048 + tid * 8;
            int row = linear >> 6;
            int col = linear & 63;
            *(bf16x8*)&As[row][col] = *(const bf16x8*)&Ab[(size_t)row * K + k0 + col];
            *(bf16x8*)&Bs[row][col] = *(const bf16x8*)&Bb[(size_t)row * K + k0 + col];
        }
        __syncthreads();
#pragma unroll
        for (int kk = 0; kk < 2; ++kk) {
            bf16x8 af[4], bfr[4];
#pragma unroll
            for (int i = 0; i < 4; ++i)
                af[i] = *(const bf16x8*)&As[wm + i * 16 + m15][kk * 32 + q4 * 8];
#pragma unroll
            for (int j = 0; j < 4; ++j)
                bfr[j] = *(const bf16x8*)&Bs[wn + j * 16 + m15][kk * 32 + q4 * 8];
#pragma unroll
            for (int i = 0; i < 4; ++i)
#pragma unroll
                for (int j = 0; j < 4; ++j)
                    acc[i][j] = mfma16(af[i], bfr[j], acc[i][j]);
        }
        __syncthreads();
    }
#pragma unroll
    for (int i = 0; i < 4; ++i)
#pragma unroll
        for (int j = 0; j < 4; ++j) {
            int row = blockIdx.x * 128 + wm + i * 16 + q4 * 4;
            int col = blockIdx.y * 128 + wn + j * 16 + m15;
#pragma unroll
            for (int r = 0; r < 4; ++r)
                C[(size_t)(row + r) * N + col] = (OutT)acc[i][j][r];
        }
}

// ---------------------------------------------------------------------------
// RoPE in-place on [B*S, nh*128]. angle = pos * 10000^(-i/64), i in [0,64).
// ---------------------------------------------------------------------------
__global__ void rope_kernel(__bf16* __restrict__ X, const int* __restrict__ pos,
                            int nh, int total) {
    int idx = blockIdx.x * blockDim.x + threadIdx.x;
    if (idx >= total) return;
    int i  = idx & 63;
    int t  = idx >> 6;
    int h  = t % nh;
    int bs = t / nh;
    float p   = (float)pos[bs];
    float inv = exp2f(-(float)i * 0.20762050593046326f);
    float ang = p * inv;
    float s, c;
    sincosf(ang, &s, &c);
    __bf16* base = X + (size_t)bs * (nh * 128) + h * 128 + i;
    float x1 = (float)base[0];
    float x2 = (float)base[64];
    base[0]  = (__bf16)(x1 * c - x2 * s);
    base[64] = (__bf16)(x2 * c + x1 * s);
}

// ---------------------------------------------------------------------------
// V transpose: V [B*S, HKV*128] -> Vt [B, HKV, 128, S].
// ---------------------------------------------------------------------------
__global__ void transpose_v(const __bf16* __restrict__ V, __bf16* __restrict__ Vt,
                            int total) {
    int idx = blockIdx.x * blockDim.x + threadIdx.x;
    if (idx >= total) return;
    int s  = idx & (S_ - 1);
    int d  = (idx >> 11) & (D_ - 1);
    int hb = idx >> 18;
    int b  = hb >> 3;
    int h  = hb & 7;
    Vt[idx] = V[((size_t)(b * S_ + s)) * (HKV_ * D_) + h * D_ + d];
}

// ---------------------------------------------------------------------------
// Block-level flash attention, causal, GQA rep=4.
// Block = 4 waves = one (b,h,128-row Q tile); wave owns 32 rows (2 rgroups).
// K-loop: stage K[64][128] + Vt[128][64] into LDS (coalesced, shared by all
// waves), QK MFMAs from LDS, online softmax, P->LDS->A-frag, PV MFMAs.
// LDS strides == 4 mod 32 dwords: b128 reads at the conflict-free minimum.
// ---------------------------------------------------------------------------
#define KSW 136
#define VSW 72
#define PSW 72

__global__ __launch_bounds__(256, 2) void attn_kernel(const __bf16* __restrict__ Q,
                                                      const __bf16* __restrict__ Kc,
                                                      const __bf16* __restrict__ Vt,
                                                      __bf16* __restrict__ O) {
    __shared__ __align__(16) __bf16 Ks[64][KSW];
    __shared__ __align__(16) __bf16 Vs[128][VSW];
    __shared__ __align__(16) __bf16 Ps[4][32 * PSW];

    const int tid  = threadIdx.x;
    const int wave = tid >> 6;
    const int lane = tid & 63;
    const int m15  = lane & 15;
    const int q4   = lane >> 4;

    const int qt = 15 - (blockIdx.x >> 6);   // longest tiles first
    const int bh = blockIdx.x & 63;
    const int b  = bh >> 5;
    const int h  = bh & 31;
    const int hkv = h >> 2;
    const int qbase = qt * 128 + wave * 32;

    // Q fragments: 2 row-groups x 4 k-chunks (A-operand layout)
    bf16x8 qf[2][4];
#pragma unroll
    for (int rg = 0; rg < 2; ++rg) {
        const __bf16* qrow = Q + ((size_t)(b * S_ + qbase + rg * 16 + m15)) * (H_ * D_) + h * D_;
#pragma unroll
        for (int kk = 0; kk < 4; ++kk) qf[rg][kk] = *(const bf16x8*)(qrow + kk * 32 + q4 * 8);
    }

    f32x4 o[2][8];
#pragma unroll
    for (int rg = 0; rg < 2; ++rg)
#pragma unroll
        for (int t = 0; t < 8; ++t) o[rg][t] = (f32x4){0.f, 0.f, 0.f, 0.f};
    float mi[2][4], li[2][4];
#pragma unroll
    for (int rg = 0; rg < 2; ++rg)
#pragma unroll
        for (int r = 0; r < 4; ++r) { mi[rg][r] = -1e9f; li[rg][r] = 0.f; }

    const __bf16* Kg = Kc + (size_t)(b * S_) * (HKV_ * D_) + hkv * D_;
    const __bf16* Vg = Vt + (size_t)((b * HKV_ + hkv) * D_) * S_;
    const float scale = 0.08838834764831845f; // 1/sqrt(128)
    __bf16* pl = &Ps[wave][0];

    const int kend = qt * 128 + 128;
    for (int kb = 0; kb < kend; kb += 64) {
        __syncthreads();   // previous iteration's readers done
        // ---- stage K tile: rows=key (64), cols=d (128)
        {
            int row = tid >> 4;            // 0..15
            int col = (tid & 15) * 8;      // 0..120
            const __bf16* src = Kg + (size_t)(kb + row) * (HKV_ * D_) + col;
#pragma unroll
            for (int p = 0; p < 4; ++p)
                *(bf16x8*)&Ks[row + p * 16][col] =
                    *(const bf16x8*)(src + (size_t)(p * 16) * (HKV_ * D_));
        }
        // ---- stage Vt tile: rows=d (128), cols=key (64)
        {
            int row = tid >> 3;            // 0..31
            int col = (tid & 7) * 8;       // 0..56
            const __bf16* src = Vg + (size_t)row * S_ + kb + col;
#pragma unroll
            for (int p = 0; p < 4; ++p)
                *(bf16x8*)&Vs[row + p * 32][col] =
                    *(const bf16x8*)(src + (size_t)(p * 32) * S_);
        }
        __syncthreads();

        if (kb <= qbase + 31) {            // skip fully-masked blocks (wave-uniform)
            // ---- QK^T: 4 key groups x 4 k-chunks x 2 row-groups
            f32x4 sg[2][4];
#pragma unroll
            for (int g = 0; g < 4; ++g) {
                bf16x8 kf[4];
#pragma unroll
                for (int kk = 0; kk < 4; ++kk)
                    kf[kk] = *(const bf16x8*)&Ks[g * 16 + m15][kk * 32 + q4 * 8];
                sg[0][g] = (f32x4){0.f, 0.f, 0.f, 0.f};
                sg[1][g] = (f32x4){0.f, 0.f, 0.f, 0.f};
#pragma unroll
                for (int kk = 0; kk < 4; ++kk) {
                    sg[0][g] = mfma16(qf[0][kk], kf[kk], sg[0][g]);
                    sg[1][g] = mfma16(qf[1][kk], kf[kk], sg[1][g]);
                }
            }
            const bool masked = (kb + 63 > qbase);   // only the causal tail blocks
            // ---- online softmax per row-group
#pragma unroll
            for (int rg = 0; rg < 2; ++rg) {
                float p[4][4], mx[4];
#pragma unroll
                for (int r = 0; r < 4; ++r) {
                    int row = qbase + rg * 16 + q4 * 4 + r;
#pragma unroll
                    for (int g = 0; g < 4; ++g) {
                        float v = sg[rg][g][r] * scale;
                        if (masked && (kb + g * 16 + m15 > row)) v = -1e9f;
                        p[g][r] = v;
                    }
                    mx[r] = fmaxf(fmaxf(p[0][r], p[1][r]), fmaxf(p[2][r], p[3][r]));
                }
#pragma unroll
                for (int off = 1; off < 16; off <<= 1)
#pragma unroll
                    for (int r = 0; r < 4; ++r) mx[r] = fmaxf(mx[r], __shfl_xor(mx[r], off));
                float al[4], rs[4];
#pragma unroll
                for (int r = 0; r < 4; ++r) {
                    float mn = fmaxf(mi[rg][r], mx[r]);
                    al[r] = __expf(mi[rg][r] - mn);
                    mi[rg][r] = mn;
#pragma unroll
                    for (int g = 0; g < 4; ++g) p[g][r] = __expf(p[g][r] - mn);
                    rs[r] = (p[0][r] + p[1][r]) + (p[2][r] + p[3][r]);
                }
#pragma unroll
                for (int off = 1; off < 16; off <<= 1)
#pragma unroll
                    for (int r = 0; r < 4; ++r) rs[r] += __shfl_xor(rs[r], off);
#pragma unroll
                for (int r = 0; r < 4; ++r) li[rg][r] = li[rg][r] * al[r] + rs[r];
#pragma unroll
                for (int t = 0; t < 8; ++t)
#pragma unroll
                    for (int r = 0; r < 4; ++r) o[rg][t][r] *= al[r];
                // P tile: C-layout -> LDS (rows 32, cols 64)
#pragma unroll
                for (int g = 0; g < 4; ++g)
#pragma unroll
                    for (int r = 0; r < 4; ++r)
                        pl[(rg * 16 + q4 * 4 + r) * PSW + g * 16 + m15] = (__bf16)p[g][r];
            }
            // ---- P A-fragments + PV
            bf16x8 pf[2][2];
#pragma unroll
            for (int rg = 0; rg < 2; ++rg)
#pragma unroll
                for (int kg = 0; kg < 2; ++kg)
                    pf[rg][kg] = *(const bf16x8*)(pl + (rg * 16 + m15) * PSW + kg * 32 + q4 * 8);
#pragma unroll
            for (int t = 0; t < 8; ++t) {
#pragma unroll
                for (int kg = 0; kg < 2; ++kg) {
                    bf16x8 vf = *(const bf16x8*)&Vs[t * 16 + m15][kg * 32 + q4 * 8];
                    o[0][t] = mfma16(pf[0][kg], vf, o[0][t]);
                    o[1][t] = mfma16(pf[1][kg], vf, o[1][t]);
                }
            }
        }
    }
    // ---- epilogue
#pragma unroll
    for (int rg = 0; rg < 2; ++rg) {
        __bf16* ob = O + ((size_t)(b * S_ + qbase + rg * 16 + q4 * 4)) * (H_ * D_) + h * D_;
#pragma unroll
        for (int t = 0; t < 8; ++t)
#pragma unroll
            for (int r = 0; r < 4; ++r)
                ob[(size_t)r * (H_ * D_) + t * 16 + m15] = (__bf16)(o[rg][t][r] / li[rg][r]);
    }
}

// ---------------------------------------------------------------------------
extern "C" void kernel_launch(void* const* d_in, const int* in_sizes, int n_in,
                              void* d_out, int out_size, void* d_ws, size_t ws_size,
                              hipStream_t stream) {
    const float* X   = (const float*)d_in[0];
    const int*   pos = (const int*)d_in[1];
    const float* Wq  = (const float*)d_in[2];
    const float* Wk  = (const float*)d_in[3];
    const float* Wv  = (const float*)d_in[4];
    const float* Wo  = (const float*)d_in[5];
    float*       out = (float*)d_out;

    char* ws = (char*)d_ws;
    __bf16* Xb   = (__bf16*)(ws);
    __bf16* Wqb  = (__bf16*)(ws + 33554432);
    __bf16* Wkb  = (__bf16*)(ws + 67108864);
    __bf16* Wvb  = (__bf16*)(ws + 75497472);
    __bf16* Wob  = (__bf16*)(ws + 83886080);
    __bf16* Qp   = (__bf16*)(ws + 117440512);
    __bf16* Kp   = (__bf16*)(ws + 150994944);
    __bf16* Vp   = (__bf16*)(ws + 159383552);
    __bf16* Vtp  = Wqb;   // alias (Wqb dead after Q-gemm)
    __bf16* Attn = Xb;    // alias (Xb dead after V-gemm)

    const int M  = B_ * S_;
    const int nX = M * DM_;
    const int nQ = H_ * D_ * DM_;
    const int nK = HKV_ * D_ * DM_;

    f32_to_bf16<<<(nX / 4 + 255) / 256, 256, 0, stream>>>(X,  Xb,  nX);
    f32_to_bf16<<<(nQ / 4 + 255) / 256, 256, 0, stream>>>(Wq, Wqb, nQ);
    f32_to_bf16<<<(nK / 4 + 255) / 256, 256, 0, stream>>>(Wk, Wkb, nK);
    f32_to_bf16<<<(nK / 4 + 255) / 256, 256, 0, stream>>>(Wv, Wvb, nK);
    f32_to_bf16<<<(nQ / 4 + 255) / 256, 256, 0, stream>>>(Wo, Wob, nQ);

    gemm_bt<__bf16><<<dim3(M / 128, DM_ / 128), 256, 0, stream>>>(Xb, Wqb, Qp, M, H_ * D_, DM_);
    gemm_bt<__bf16><<<dim3(M / 128, (HKV_ * D_) / 128), 256, 0, stream>>>(Xb, Wkb, Kp, M, HKV_ * D_, DM_);
    gemm_bt<__bf16><<<dim3(M / 128, (HKV_ * D_) / 128), 256, 0, stream>>>(Xb, Wvb, Vp, M, HKV_ * D_, DM_);
    {
        int totq = M * H_ * 64;
        rope_kernel<<<(totq + 255) / 256, 256, 0, stream>>>(Qp, pos, H_, totq);
        int totk = M * HKV_ * 64;
        rope_kernel<<<(totk + 255) / 256, 256, 0, stream>>>(Kp, pos, HKV_, totk);
    }
    {
        int tot = B_ * HKV_ * D_ * S_;
        transpose_v<<<(tot + 255) / 256, 256, 0, stream>>>(Vp, Vtp, tot);
    }
    // attention: 1024 blocks = (b,h,qtile of 128 rows), longest-first
    attn_kernel<<<B_ * H_ * (S_ / 128), 256, 0, stream>>>(Qp, Kp, Vtp, Attn);
    gemm_bt<float><<<dim3(M / 128, (H_ * D_) / 128), 256, 0, stream>>>(Attn, Wob, out, M, H_ * D_, DM_);
}